// Round 10
// baseline (201.275 us; speedup 1.0000x reference)
//
#include <hip/hip_runtime.h>
#include <math.h>

// Problem constants
constexpr int LQ  = 1024;   // sequence length
constexpr int NH  = 32;     // heads
constexpr int HDM = 64;     // head dim
constexpr int FDM = 64;     // feature dim
constexpr int HID = 2048;   // NH*HDM
constexpr int NCH = 16;     // chunks
constexpr int CT  = 64;     // chunk length (NCH*CT == LQ)
#define EPSV 1e-12f

typedef __bf16 bf16x8 __attribute__((ext_vector_type(8)));
typedef float  f32x4  __attribute__((ext_vector_type(4)));

// fp32 -> bf16 raw bits, round-to-nearest-even
__device__ __forceinline__ unsigned short f2b_raw(float x) {
    union { float f; unsigned int u; } v; v.f = x;
    unsigned int r = v.u + 0x7fffu + ((v.u >> 16) & 1u);
    return (unsigned short)(r >> 16);
}
__device__ __forceinline__ float b2f(ushort u) {
    union { unsigned int i; float f; } v; v.i = ((unsigned int)u) << 16; return v.f;
}

// async global->LDS, 16B per lane; lds dst = wave-uniform base + lane*16
#define ASYNC16(ldsp, gp) __builtin_amdgcn_global_load_lds( \
    (const __attribute__((address_space(1))) void*)(gp),    \
    (__attribute__((address_space(3))) void*)(ldsp), 16, 0, 0)

// ---------------------------------------------------------------------------
// Generic bf16 MFMA GEMM core (NT), BK=64, double-buffered, XOR-swizzled LDS.
// NOTE (R7): 128x128 tile at M=1024 -> 1.5 blk/CU, VGPR 140 -> 2x slower.
// NOTE (R8): replacing MFMA state kernel with a scalar register scan cost
// +30 us (serial LDS-latency chain). Keep MFMA for anything matmul-shaped.
// ---------------------------------------------------------------------------
template <int TM, int TN, bool BF16OUT>
__device__ __forceinline__ void gemm_core(const ushort* __restrict__ A,
                                          const ushort* __restrict__ B,
                                          void* __restrict__ Cv,
                                          int M, int N, int K) {
    constexpr int FI = TM / 32, FJ = TN / 32;
    constexpr int AI = TM / 32, BJ = TN / 32;
    constexpr int ASZ = TM * 64, BSZ = TN * 64;
    __shared__ __align__(16) ushort As[2 * ASZ];
    __shared__ __align__(16) ushort Bs[2 * BSZ];

    const int t = threadIdx.x, wave = t >> 6, lane = t & 63;
    const int wr = (wave >> 1) * (TM / 2), wc = (wave & 1) * (TN / 2);
    const int bm = blockIdx.y * TM, bn = blockIdx.x * TN;

    const int grow = lane >> 3;
    const int gsw  = ((lane & 7) ^ (grow & 7)) << 3;
    const int arow0 = wave * (TM / 4), brow0 = wave * (TN / 4);
    const ushort* gA = A + (size_t)(bm + arow0 + grow) * K + gsw;
    const ushort* gB = B + (size_t)(bn + brow0 + grow) * K + gsw;

    const int fr = lane & 15, q = lane >> 4;

    f32x4 acc[FI][FJ] = {};
    const int NIT = K >> 6;

    {
        ushort* ab = As + arow0 * 64;
        ushort* bb = Bs + brow0 * 64;
#pragma unroll
        for (int i = 0; i < AI; ++i) ASYNC16(ab + i * 512, gA + (size_t)i * 8 * K);
#pragma unroll
        for (int j = 0; j < BJ; ++j) ASYNC16(bb + j * 512, gB + (size_t)j * 8 * K);
    }
    __syncthreads();

    for (int it = 0; it < NIT; ++it) {
        const int p = it & 1;
        if (it + 1 < NIT) {
            const int ko = (it + 1) << 6;
            ushort* ab = As + (p ^ 1) * ASZ + arow0 * 64;
            ushort* bb = Bs + (p ^ 1) * BSZ + brow0 * 64;
#pragma unroll
            for (int i = 0; i < AI; ++i) ASYNC16(ab + i * 512, gA + ko + (size_t)i * 8 * K);
#pragma unroll
            for (int j = 0; j < BJ; ++j) ASYNC16(bb + j * 512, gB + ko + (size_t)j * 8 * K);
        }
        const ushort* ap = As + p * ASZ;
        const ushort* bp = Bs + p * BSZ;
        bf16x8 af[2][FI], bg[2][FJ];
#pragma unroll
        for (int ks = 0; ks < 2; ++ks) {
#pragma unroll
            for (int i = 0; i < FI; ++i) {
                const int row = wr + i * 16 + fr;
                af[ks][i] = *(const bf16x8*)&ap[row * 64 + (((q + ks * 4) ^ (row & 7)) << 3)];
            }
#pragma unroll
            for (int j = 0; j < FJ; ++j) {
                const int row = wc + j * 16 + fr;
                bg[ks][j] = *(const bf16x8*)&bp[row * 64 + (((q + ks * 4) ^ (row & 7)) << 3)];
            }
        }
#pragma unroll
        for (int ks = 0; ks < 2; ++ks)
#pragma unroll
            for (int i = 0; i < FI; ++i)
#pragma unroll
                for (int j = 0; j < FJ; ++j)
                    acc[i][j] = __builtin_amdgcn_mfma_f32_16x16x32_bf16(af[ks][i], bg[ks][j], acc[i][j], 0, 0, 0);
        if (it + 1 < NIT) __syncthreads();
    }

    const int er = q * 4, ec = lane & 15;
#pragma unroll
    for (int i = 0; i < FI; ++i)
#pragma unroll
        for (int j = 0; j < FJ; ++j) {
            const size_t base = (size_t)(bm + wr + i * 16 + er) * N + bn + wc + j * 16 + ec;
            if constexpr (BF16OUT) {
                ushort* C = (ushort*)Cv;
#pragma unroll
                for (int r = 0; r < 4; ++r) C[base + (size_t)r * N] = f2b_raw(acc[i][j][r]);
            } else {
                float* C = (float*)Cv;
#pragma unroll
                for (int r = 0; r < 4; ++r) C[base + (size_t)r * N] = acc[i][j][r];
            }
        }
}

__global__ __launch_bounds__(256) void gemm_one(const ushort* __restrict__ A,
                                                const ushort* __restrict__ B,
                                                float* __restrict__ C) {
    gemm_core<64, 64, false>(A, B, C, LQ, HID, HID);
}

// ---------------------------------------------------------------------------
// Fused QKV projection + feature map (z=0: Q->fqB, z=1: K->fkB) or
// transposed V store (z=2: ->VTb [h][c][d][l]).
// Tile 64(M=one chunk) x 128(N=two heads), BK=64, dbuf, XOR swizzle.
// (R6-verified: 39.8 us, VGPR 68, MfmaUtil 27%.)
// ---------------------------------------------------------------------------
__global__ __launch_bounds__(256) void gemm_qkv_fm(
    const ushort* __restrict__ hsb,
    const ushort* __restrict__ wqb, const ushort* __restrict__ wkb,
    const ushort* __restrict__ wvb,
    const ushort* __restrict__ WfqT, const ushort* __restrict__ WfkT,
    ushort* __restrict__ fqB, ushort* __restrict__ fkB,
    ushort* __restrict__ VTb) {
    constexpr int TM = 64, TN = 128;
    constexpr int ASZ = TM * 64, BSZ = TN * 64;       // 4096 / 8192 ushort
    __shared__ __align__(16) ushort lds[2 * ASZ + 2 * BSZ];   // 24576 ushort = 48 KB
    ushort* As = lds;
    ushort* Bs = lds + 2 * ASZ;

    const int z = blockIdx.z;
    const ushort* Bmat = (z == 0) ? wqb : (z == 1) ? wkb : wvb;

    const int t = threadIdx.x, wave = t >> 6, lane = t & 63;
    const int wr = (wave >> 1) * 32, wc = (wave & 1) * 64;
    const int bx = blockIdx.x, c = blockIdx.y;
    const int bm = c * TM, bn = bx * TN, l0 = c * CT;

    const int grow = lane >> 3;
    const int gsw  = ((lane & 7) ^ (grow & 7)) << 3;
    const int arow0 = wave * 16, brow0 = wave * 32;
    const ushort* gA = hsb  + (size_t)(bm + arow0 + grow) * HID + gsw;
    const ushort* gB = Bmat + (size_t)(bn + brow0 + grow) * HID + gsw;

    const int fr = lane & 15, q = lane >> 4, ec = lane & 15;

    f32x4 acc[2][4] = {};
    const int NIT = HID >> 6;   // 32

    {
        ushort* ab = As + arow0 * 64;
        ushort* bb = Bs + brow0 * 64;
#pragma unroll
        for (int i = 0; i < 2; ++i) ASYNC16(ab + i * 512, gA + (size_t)i * 8 * HID);
#pragma unroll
        for (int j = 0; j < 4; ++j) ASYNC16(bb + j * 512, gB + (size_t)j * 8 * HID);
    }
    __syncthreads();

    for (int it = 0; it < NIT; ++it) {
        const int p = it & 1;
        if (it + 1 < NIT) {
            const int ko = (it + 1) << 6;
            ushort* ab = As + (p ^ 1) * ASZ + arow0 * 64;
            ushort* bb = Bs + (p ^ 1) * BSZ + brow0 * 64;
#pragma unroll
            for (int i = 0; i < 2; ++i) ASYNC16(ab + i * 512, gA + ko + (size_t)i * 8 * HID);
#pragma unroll
            for (int j = 0; j < 4; ++j) ASYNC16(bb + j * 512, gB + ko + (size_t)j * 8 * HID);
        }
        const ushort* ap = As + p * ASZ;
        const ushort* bp = Bs + p * BSZ;
        bf16x8 af[2][2], bg[2][4];
#pragma unroll
        for (int ks = 0; ks < 2; ++ks) {
#pragma unroll
            for (int i = 0; i < 2; ++i) {
                const int row = wr + i * 16 + fr;
                af[ks][i] = *(const bf16x8*)&ap[row * 64 + (((q + ks * 4) ^ (row & 7)) << 3)];
            }
#pragma unroll
            for (int j = 0; j < 4; ++j) {
                const int row = wc + j * 16 + fr;
                bg[ks][j] = *(const bf16x8*)&bp[row * 64 + (((q + ks * 4) ^ (row & 7)) << 3)];
            }
        }
#pragma unroll
        for (int ks = 0; ks < 2; ++ks)
#pragma unroll
            for (int i = 0; i < 2; ++i)
#pragma unroll
                for (int j = 0; j < 4; ++j)
                    acc[i][j] = __builtin_amdgcn_mfma_f32_16x16x32_bf16(af[ks][i], bg[ks][j], acc[i][j], 0, 0, 0);
        if (it + 1 < NIT) __syncthreads();
    }

    if (z == 2) {
        // transposed V store: r is contiguous in l -> ushort4
#pragma unroll
        for (int i = 0; i < 2; ++i)
#pragma unroll
            for (int j = 0; j < 4; ++j) {
                const int col = wc + j * 16 + ec;        // 0..127
                const int hh = col >> 6, d = col & 63;
                const int lb = wr + i * 16 + q * 4;
                const size_t base = (((size_t)(2 * bx + hh) * NCH + c) * 64 + d) * 64 + lb;
                ushort4 o = make_ushort4(f2b_raw(acc[i][j][0]), f2b_raw(acc[i][j][1]),
                                         f2b_raw(acc[i][j][2]), f2b_raw(acc[i][j][3]));
                *(ushort4*)&VTb[base] = o;
            }
        return;
    }

    // ---- fused feature map ----
    __syncthreads();                       // all LDS reads of K-loop done
    ushort* Qt  = lds;                     // [64][136] bf16 projection tile
    ushort* Wfs = lds + 8704;              // [2][64][72] WfT for heads 2bx,2bx+1
#pragma unroll
    for (int i = 0; i < 2; ++i)
#pragma unroll
        for (int j = 0; j < 4; ++j)
#pragma unroll
            for (int r = 0; r < 4; ++r)
                Qt[(wr + i * 16 + q * 4 + r) * 136 + wc + j * 16 + ec] = f2b_raw(acc[i][j][r]);
    {
        const ushort* WT = ((z == 0) ? WfqT : WfkT) + (size_t)(2 * bx) * 4096;
#pragma unroll
        for (int it = 0; it < 4; ++it) {
            const int e = it * 2048 + t * 8;
            const int hh = e >> 12, f = (e >> 6) & 63, dc = e & 63;
            uint4 wv4 = *(const uint4*)&WT[e];
            *(uint4*)&Wfs[hh * 4608 + f * 72 + dc] = wv4;
        }
    }
    __syncthreads();

    // Z = Qhead @ WfT^T  : wave -> head (wave&1), rows (wave>>1)*32..+32
    const int hh = wave & 1, R0 = (wave >> 1) * 32;
    f32x4 z2[2][4] = {};
#pragma unroll
    for (int ks = 0; ks < 2; ++ks) {
        bf16x8 a[2];
#pragma unroll
        for (int i = 0; i < 2; ++i)
            a[i] = *(const bf16x8*)&Qt[(R0 + i * 16 + fr) * 136 + hh * 64 + ks * 32 + q * 8];
#pragma unroll
        for (int j = 0; j < 4; ++j) {
            bf16x8 b = *(const bf16x8*)&Wfs[hh * 4608 + (j * 16 + fr) * 72 + ks * 32 + q * 8];
#pragma unroll
            for (int i = 0; i < 2; ++i)
                z2[i][j] = __builtin_amdgcn_mfma_f32_16x16x32_bf16(a[i], b, z2[i][j], 0, 0, 0);
        }
    }

    // softmax over f per row, entirely in registers (16-lane quad groups)
    ushort* outp = (z == 0) ? fqB : fkB;
    const int hgl = 2 * bx + hh;
#pragma unroll
    for (int i = 0; i < 2; ++i)
#pragma unroll
        for (int r = 0; r < 4; ++r) {
            float m = z2[i][0][r];
#pragma unroll
            for (int j = 1; j < 4; ++j) m = fmaxf(m, z2[i][j][r]);
            m = fmaxf(m, __shfl_xor(m, 1)); m = fmaxf(m, __shfl_xor(m, 2));
            m = fmaxf(m, __shfl_xor(m, 4)); m = fmaxf(m, __shfl_xor(m, 8));
            float e4[4], s = 0.f;
#pragma unroll
            for (int j = 0; j < 4; ++j) { e4[j] = __expf(z2[i][j][r] - m); s += e4[j]; }
            s += __shfl_xor(s, 1); s += __shfl_xor(s, 2);
            s += __shfl_xor(s, 4); s += __shfl_xor(s, 8);
            const float inv = 1.0f / s;
            const int l = R0 + i * 16 + q * 4 + r;
            ushort* op = outp + ((size_t)hgl * LQ + l0 + l) * FDM;
#pragma unroll
            for (int j = 0; j < 4; ++j) op[j * 16 + ec] = f2b_raw(e4[j] * inv);
        }
}

// ---------------------------------------------------------------------------
// Convert, tight 1D grid: blocks [0, 18432) do fp32->bf16 vec4 groups across
// hs + 4 weights (flat index decode); blocks [18432, 18496) do Wf transpose.
// ---------------------------------------------------------------------------
struct ConvArgs {
    const float* src[5]; ushort* dst[5];
    const float* Wfq; const float* Wfk; ushort* WfqT; ushort* WfkT;
};
__global__ __launch_bounds__(256) void conv_all(ConvArgs p) {
    const int b = blockIdx.x, t = threadIdx.x;
    if (b < 18432) {
        int g = b * 256 + t;                 // vec4 group index
        int which; int off;
        if (g < 524288) { which = 0; off = g; }                    // hs: SZ/4
        else { g -= 524288; which = 1 + (g >> 20); off = g & 1048575; }  // WZ/4 each
        const size_t e = (size_t)off * 4;
        float4 v = *(const float4*)&p.src[which][e];
        ushort4 o = make_ushort4(f2b_raw(v.x), f2b_raw(v.y), f2b_raw(v.z), f2b_raw(v.w));
        *(ushort4*)&p.dst[which][e] = o;
        return;
    }
    const int idx = b - 18432, h = idx & 31, isK = idx >> 5;
    const float* src = (isK ? p.Wfk : p.Wfq) + (size_t)h * 4096;   // [d][f]
    ushort* dst = (isK ? p.WfkT : p.WfqT) + (size_t)h * 4096;      // [f][d]
    __shared__ float tile[64][65];
    for (int it = 0; it < 16; ++it) {
        int e = it * 256 + t; int d = e >> 6, f = e & 63;
        tile[d][f] = src[e];
    }
    __syncthreads();
    for (int it = 0; it < 16; ++it) {
        int e = it * 256 + t; int f = e >> 6, d = e & 63;
        dst[e] = f2b_raw(tile[d][f]);
    }
}

// ---------------------------------------------------------------------------
// Per-chunk KV state via MFMA: St[d][f] = sum_l VT[d][l]*fk[l][f]; Ks[f].
// grid (NCH, NH), block 256.  (R6-verified path.)
// ---------------------------------------------------------------------------
__global__ __launch_bounds__(256) void chunk_state(
    const ushort* __restrict__ fkB, const ushort* __restrict__ VTb,
    float* __restrict__ Sraw, float* __restrict__ Ks) {
    __shared__ __align__(16) ushort Vs[64 * 72];   // [d][l]
    __shared__ __align__(16) ushort Fs[64 * 72];   // [f][l]
    const int c = blockIdx.x, h = blockIdx.y;
    const int t = threadIdx.x, lane = t & 63, w = t >> 6;
    const int l0 = c * CT;
    const int fr = lane & 15, q = lane >> 4, ec = lane & 15;
    const size_t cb = ((size_t)h * NCH + c) * 4096;

    for (int it = 0; it < 2; ++it) {
        const int e = (it * 256 + t) * 8;
        const int row = e >> 6, col = e & 63;
        *(uint4*)&Vs[row * 72 + col] = *(const uint4*)&VTb[cb + e];
        uint4 fv = *(const uint4*)&fkB[((size_t)h * LQ + l0) * FDM + e];
        const ushort* pf = (const ushort*)&fv;
#pragma unroll
        for (int i2 = 0; i2 < 8; ++i2) Fs[(col + i2) * 72 + row] = pf[i2];
    }
    __syncthreads();

    f32x4 acc[4] = {};
#pragma unroll
    for (int ks = 0; ks < 2; ++ks) {
        bf16x8 a = *(const bf16x8*)&Vs[(w * 16 + fr) * 72 + ks * 32 + q * 8];
#pragma unroll
        for (int j = 0; j < 4; ++j) {
            bf16x8 b = *(const bf16x8*)&Fs[(j * 16 + fr) * 72 + ks * 32 + q * 8];
            acc[j] = __builtin_amdgcn_mfma_f32_16x16x32_bf16(a, b, acc[j], 0, 0, 0);
        }
    }
    float* sp = Sraw + cb;
#pragma unroll
    for (int j = 0; j < 4; ++j)
#pragma unroll
        for (int r = 0; r < 4; ++r)
            sp[(w * 16 + q * 4 + r) * 64 + j * 16 + ec] = acc[j][r];
    if (t < 64) {
        float s = 0.f;
#pragma unroll 8
        for (int l = 0; l < 64; ++l) s += b2f(Fs[t * 72 + l]);
        Ks[((size_t)h * NCH + c) * FDM + t] = s;
    }
}

// ---------------------------------------------------------------------------
// Intra-chunk attention via MFMA, with in-block exclusive prefix of the
// KV state (reads Sraw/Ks directly; prefix2 kernel deleted — the avg
// 7.5x16KB of fp32 re-reads are L2/LLC-served, cheaper than a launch).
// ---------------------------------------------------------------------------
__global__ __launch_bounds__(256) void intra2(
    const ushort* __restrict__ fqB, const ushort* __restrict__ fkB,
    const ushort* __restrict__ VTb, const float* __restrict__ Sraw,
    const float* __restrict__ Ks, ushort* __restrict__ Yb) {
    __shared__ __align__(16) ushort fqs[64 * 72];
    __shared__ __align__(16) ushort fks[64 * 72];
    __shared__ __align__(16) ushort VTs[64 * 72];
    __shared__ __align__(16) ushort Sps[64 * 72];
    __shared__ __align__(16) ushort Pms[64 * 72];
    __shared__ float den[64], kpr[64];

    const int c = blockIdx.x, h = blockIdx.y;
    const int t = threadIdx.x, lane = t & 63, wave = t >> 6;
    const int l0 = c * CT;
    const int fr = lane & 15, fo = (lane >> 4) * 8;
    const int g = lane >> 4, cc = lane & 15;

    const size_t qkbase = ((size_t)h * LQ + l0) * FDM;
    const size_t cbase  = ((size_t)h * NCH + c) * 4096;
    for (int it = 0; it < 2; ++it) {
        int e = (it * 256 + t) * 8;
        int row = e >> 6, col = e & 63;
        *(uint4*)&fqs[row * 72 + col] = *(const uint4*)&fqB[qkbase + e];
        *(uint4*)&fks[row * 72 + col] = *(const uint4*)&fkB[qkbase + e];
        *(uint4*)&VTs[row * 72 + col] = *(const uint4*)&VTb[cbase + e];
    }
    // exclusive prefix of state over chunks < c (fp32 acc -> one bf16 round,
    // numerically identical to the old prefix2 path)
    {
        float pre[16] = {};
        const size_t hb = (size_t)h * NCH * 4096;
        for (int c2 = 0; c2 < c; ++c2) {
            const float* sp = Sraw + hb + (size_t)c2 * 4096 + t * 16;
#pragma unroll
            for (int i = 0; i < 16; i += 4) {
                float4 v = *(const float4*)&sp[i];
                pre[i] += v.x; pre[i + 1] += v.y; pre[i + 2] += v.z; pre[i + 3] += v.w;
            }
        }
        const int row = (t * 16) >> 6, col = (t * 16) & 63;
        ushort o[16];
#pragma unroll
        for (int i = 0; i < 16; ++i) o[i] = f2b_raw(pre[i]);
        *(uint4*)&Sps[row * 72 + col]     = *(uint4*)&o[0];
        *(uint4*)&Sps[row * 72 + col + 8] = *(uint4*)&o[8];
        if (t < 64) {
            float rk = 0.f;
            for (int c2 = 0; c2 < c; ++c2) rk += Ks[((size_t)h * NCH + c2) * FDM + t];
            kpr[t] = rk;
        }
    }
    __syncthreads();

    // P = fq @ fk^T
    f32x4 accP[4] = {};
#pragma unroll
    for (int kp = 0; kp < 2; ++kp) {
        bf16x8 a = *(const bf16x8*)&fqs[(wave * 16 + fr) * 72 + kp * 32 + fo];
#pragma unroll
        for (int j = 0; j < 4; ++j) {
            bf16x8 b = *(const bf16x8*)&fks[(j * 16 + fr) * 72 + kp * 32 + fo];
            accP[j] = __builtin_amdgcn_mfma_f32_16x16x32_bf16(a, b, accP[j], 0, 0, 0);
        }
    }
#pragma unroll
    for (int j = 0; j < 4; ++j)
#pragma unroll
        for (int r = 0; r < 4; ++r) {
            int l = wave * 16 + g * 4 + r, lp = j * 16 + cc;
            Pms[l * 72 + lp] = (lp <= l) ? f2b_raw(accP[j][r]) : (ushort)0;
        }
    __syncthreads();

    // denominator, 4 threads/row
    {
        const int srow = t >> 2, spart = t & 3;
        float s = 0.f;
#pragma unroll
        for (int i = 0; i < 16; ++i) s += b2f(Pms[srow * 72 + spart * 16 + i]);
#pragma unroll
        for (int i = 0; i < 16; ++i) s += b2f(fqs[srow * 72 + spart * 16 + i]) * kpr[spart * 16 + i];
        s += __shfl_xor(s, 1); s += __shfl_xor(s, 2);
        if (spart == 0) den[srow] = s + EPSV;
    }
    __syncthreads();

    // Y = Pm @ V + fq @ Spre^T
    f32x4 accY[4] = {};
#pragma unroll
    for (int kp = 0; kp < 2; ++kp) {
        bf16x8 a = *(const bf16x8*)&Pms[(wave * 16 + fr) * 72 + kp * 32 + fo];
#pragma unroll
        for (int j = 0; j < 4; ++j) {
            bf16x8 b = *(const bf16x8*)&VTs[(j * 16 + fr) * 72 + kp * 32 + fo];
            accY[j] = __builtin_amdgcn_mfma_f32_16x16x32_bf16(a, b, accY[j], 0, 0, 0);
        }
    }
#pragma unroll
    for (int kp = 0; kp < 2; ++kp) {
        bf16x8 a = *(const bf16x8*)&fqs[(wave * 16 + fr) * 72 + kp * 32 + fo];
#pragma unroll
        for (int j = 0; j < 4; ++j) {
            bf16x8 b = *(const bf16x8*)&Sps[(j * 16 + fr) * 72 + kp * 32 + fo];
            accY[j] = __builtin_amdgcn_mfma_f32_16x16x32_bf16(a, b, accY[j], 0, 0, 0);
        }
    }
#pragma unroll
    for (int r = 0; r < 4; ++r) {
        int l = wave * 16 + g * 4 + r;
        float inv = 1.0f / den[l];
        ushort* yo = Yb + (size_t)(l0 + l) * HID + h * HDM;
#pragma unroll
        for (int j = 0; j < 4; ++j)
            yo[j * 16 + cc] = f2b_raw(accY[j][r] * inv);
    }
}

// ---------------------------------------------------------------------------
extern "C" void kernel_launch(void* const* d_in, const int* in_sizes, int n_in,
                              void* d_out, int out_size, void* d_ws, size_t ws_size,
                              hipStream_t stream) {
    const float* hs  = (const float*)d_in[0];
    const float* Wq  = (const float*)d_in[1];
    const float* Wk  = (const float*)d_in[2];
    const float* Wv  = (const float*)d_in[3];
    const float* Wo  = (const float*)d_in[4];
    const float* Wfq = (const float*)d_in[5];
    const float* Wfk = (const float*)d_in[6];
    float* out = (float*)d_out;

    const size_t SZ = (size_t)LQ * HID;          // 2,097,152
    const size_t WZ = (size_t)HID * HID;         // 4,194,304

    char* w = (char*)d_ws;
    auto aus = [&](size_t n) { ushort* p = (ushort*)w; w += n * sizeof(ushort); return p; };
    auto afl = [&](size_t n) { float*  p = (float*)w;  w += n * sizeof(float);  return p; };

    ushort* hsb   = aus(SZ);
    ushort* wqb   = aus(WZ);
    ushort* wkb   = aus(WZ);
    ushort* wvb   = aus(WZ);
    ushort* wob   = aus(WZ);
    ushort* fqB   = aus(SZ);
    ushort* fkB   = aus(SZ);
    ushort* VTb   = aus(SZ);
    ushort* WfqT  = aus((size_t)NH * 4096);
    ushort* WfkT  = aus((size_t)NH * 4096);
    ushort* Yb    = aus(SZ);
    float*  Sraw  = afl(SZ);
    float*  Ks    = afl((size_t)NH * NCH * FDM);

    ConvArgs ca;
    ca.src[0] = hs; ca.dst[0] = hsb;
    ca.src[1] = Wq; ca.dst[1] = wqb;
    ca.src[2] = Wk; ca.dst[2] = wkb;
    ca.src[3] = Wv; ca.dst[3] = wvb;
    ca.src[4] = Wo; ca.dst[4] = wob;
    ca.Wfq = Wfq; ca.Wfk = Wfk; ca.WfqT = WfqT; ca.WfkT = WfkT;
    conv_all<<<18496, 256, 0, stream>>>(ca);

    // 64x128 tiles: grid (16, 16, 3) = 768 blocks = 3 blocks/CU
    gemm_qkv_fm<<<dim3(HID / 128, LQ / 64, 3), 256, 0, stream>>>(
        hsb, wqb, wkb, wvb, WfqT, WfkT, fqB, fkB, VTb);

    chunk_state<<<dim3(NCH, NH), 256, 0, stream>>>(fkB, VTb, Sraw, Ks);

    intra2<<<dim3(NCH, NH), 256, 0, stream>>>(fqB, fkB, VTb, Sraw, Ks, Yb);

    // 64x64 tile: grid 32 x 16 = 512 blocks = 2 blocks/CU
    gemm_one<<<dim3(HID / 64, LQ / 64), 256, 0, stream>>>(Yb, wob, out);
}